// Round 6
// baseline (327.346 us; speedup 1.0000x reference)
//
#include <hip/hip_runtime.h>

#define NB 4096
#define NT 512
#define BPB 8    // batches per block (MFMA cols 8..15 duplicate 0..7)
#define HS 40    // ushort stride per batch row (80 B: 16B-aligned)

typedef float f32x4 __attribute__((ext_vector_type(4)));
typedef short bf16x8 __attribute__((ext_vector_type(8)));

__device__ __forceinline__ float fsig(float x) {
    return __builtin_amdgcn_rcpf(1.0f + __expf(-x));
}
__device__ __forceinline__ float ftanh(float x) {
    return 2.0f * __builtin_amdgcn_rcpf(1.0f + __expf(-2.0f * x)) - 1.0f;
}
// one inst packs two f32->bf16: result = [bf16(a) | bf16(b)<<16]
__device__ __forceinline__ unsigned cvt_pk_bf16(float a, float b) {
    unsigned r;
    asm("v_cvt_pk_bf16_f32 %0, %1, %2" : "=v"(r) : "v"(a), "v"(b));
    return r;
}
// RTNE f32->bf16 (prologue / weight prep only)
__device__ __forceinline__ unsigned short f2bf(float f) {
    unsigned u = __builtin_bit_cast(unsigned, f);
    u += 0x7fffu + ((u >> 16) & 1u);
    return (unsigned short)(u >> 16);
}
__device__ __forceinline__ float bf2f(unsigned short h) {
    return __builtin_bit_cast(float, (unsigned)h << 16);
}

// 512 blocks x 8 waves x 8 batches (2 blocks/CU -> 4 waves/SIMD; two
// independent recurrences overlap per CU). Per step, wave w computes its
// 16-row gate tile with an INDEPENDENT hi/lo MFMA pair (h split bf16 ->
// near-fp32), C/D layout (col=lane&15=batch, row-group=(lane>>4)) giving
// lane all 4 gates of hidden j=4*wid+g -> activations in-register, one
// barrier/step. th staged bf16 in a double-buffered 8-step chunk; every 8th
// step wave w computes the head for its time-slice with one MFMA pair.
__global__ __launch_bounds__(512, 2) void lstm_mfma_kernel(
    const float* __restrict__ x,
    const float* __restrict__ W_ih,
    const float* __restrict__ W_hh,
    const float* __restrict__ b_ih,
    const float* __restrict__ b_hh,
    const float* __restrict__ W1,
    const float* __restrict__ b1,
    const float* __restrict__ W2,
    const float* __restrict__ b2,
    float* __restrict__ out)
{
    const int tid  = threadIdx.x;
    const int wid  = tid >> 6;
    const int lane = tid & 63;
    const int g    = lane >> 4;     // row-group (C rows 4g..4g+3)
    const int n    = lane & 15;     // batch column (8..15 duplicate 0..7)
    const int j    = 4 * wid + g;   // hidden unit owned by this lane
    const int batch0 = blockIdx.x * BPB;

    __shared__ __align__(16) unsigned short sh_h[2][2][16][HS]; // [buf][hi/lo][n][j]
    __shared__ __align__(16) unsigned short sh_t[2][8][16][HS]; // [buf][tc][n][j] tanh(h)

    // ---- gate A fragment: lane holds row m=lane&15, k = 8g..8g+7 of the
    //      permuted W_hh tile (row m -> gate (m&3), hidden 4*wid+(m>>2)) ----
    bf16x8 afrag;
    {
        const int m = lane & 15;
        const int grow = (m & 3) * 32 + 4 * wid + (m >> 2);
        const float* wp = W_hh + grow * 32 + 8 * g;
#pragma unroll
        for (int i = 0; i < 8; ++i) afrag[i] = (short)f2bf(wp[i]);
    }

    // ---- per-lane gate params for hidden j: rows r*32+j ----
    float wihx[4], wihy[4], bias[4];
#pragma unroll
    for (int r = 0; r < 4; ++r) {
        const int row = r * 32 + j;
        wihx[r] = W_ih[row * 2 + 0];
        wihy[r] = W_ih[row * 2 + 1];
        bias[r] = b_ih[row] + b_hh[row];
    }

    // ---- head A fragment: W1 rows m=lane&15, split bf16 hi+lo ----
    bf16x8 w1hi, w1lo;
    {
        const float* wp = W1 + (lane & 15) * 32 + 8 * g;
#pragma unroll
        for (int i = 0; i < 8; ++i) {
            const float w = wp[i];
            const unsigned short hi = f2bf(w);
            w1hi[i] = (short)hi;
            w1lo[i] = (short)f2bf(w - bf2f(hi));
        }
    }
    float b1r[4], w2r[4];   // fc1 output d = 4g+r
#pragma unroll
    for (int r = 0; r < 4; ++r) {
        b1r[r] = b1[4 * g + r];
        w2r[r] = W2[4 * g + r];
    }
    const float b2v = b2[0];

    // ---- zero-init h state ----
    {
        unsigned short* ph = (unsigned short*)sh_h;
        for (int i = tid; i < 2 * 2 * 16 * HS; i += 512) ph[i] = 0;
    }
    __syncthreads();

    // lanes 8..15 mirror batch n-8 (in-bounds, duplicated work, no NaNs)
    const float2* xp = (const float2*)x + (size_t)(batch0 + (n & 7)) * NT;
    float2 xv = xp[0];
    float c = 0.0f;
    float* outB = out + (size_t)batch0 * NT;

    int cur = 0;
    for (int t = 0; t < NT; ++t) {
        // C init = biases + W_ih * x_t (fp32)
        f32x4 acc;
#pragma unroll
        for (int r = 0; r < 4; ++r)
            acc[r] = fmaf(xv.x, wihx[r], fmaf(xv.y, wihy[r], bias[r]));
        f32x4 accL = {0.0f, 0.0f, 0.0f, 0.0f};

        // gates += W_hh*h_hi  and (independently) W_hh*h_lo; latencies overlap
        const bf16x8 bhi = *(const bf16x8*)&sh_h[cur][0][n][8 * g];
        const bf16x8 blo = *(const bf16x8*)&sh_h[cur][1][n][8 * g];
        acc  = __builtin_amdgcn_mfma_f32_16x16x32_bf16(afrag, bhi, acc,  0, 0, 0);
        accL = __builtin_amdgcn_mfma_f32_16x16x32_bf16(afrag, blo, accL, 0, 0, 0);

        const float2 xn = xp[(t + 1 < NT) ? t + 1 : t];   // prefetch

        // ---- activations (lane owns batch n, hidden j; c stays in reg) ----
        const float ig = fsig(acc[0] + accL[0]);
        const float fg = fsig(acc[1] + accL[1]);
        const float gg = ftanh(acc[2] + accL[2]);
        const float og = fsig(acc[3] + accL[3]);
        c = fmaf(fg, c, ig * gg);
        const float hk  = og * ftanh(c);
        const float thk = ftanh(hk);

        // ---- pack: pk0 = [bf16(hk) | bf16(thk)<<16]; hlo = residual ----
        const unsigned pk0 = cvt_pk_bf16(hk, thk);
        const float hlo = hk - __builtin_bit_cast(float, pk0 << 16);
        const unsigned pk1 = cvt_pk_bf16(hlo, hlo);

        const int nxt = cur ^ 1;
        const int tb  = (t >> 3) & 1;
        sh_h[nxt][0][n][j] = (unsigned short)pk0;            // h hi
        sh_h[nxt][1][n][j] = (unsigned short)pk1;            // h lo (residual)
        sh_t[tb][t & 7][n][j] = (unsigned short)(pk0 >> 16); // tanh(h)
        __syncthreads();   // the one barrier: h(t)/th(t) visible to all waves

        // ---- every 8 steps: wave wid computes head for time t-7+wid ----
        if ((t & 7) == 7) {
            const bf16x8 bth = *(const bf16x8*)&sh_t[tb][wid][n][8 * g];
            f32x4 hacc;
#pragma unroll
            for (int r = 0; r < 4; ++r) hacc[r] = b1r[r];
            hacc = __builtin_amdgcn_mfma_f32_16x16x32_bf16(w1hi, bth, hacc, 0, 0, 0);
            hacc = __builtin_amdgcn_mfma_f32_16x16x32_bf16(w1lo, bth, hacc, 0, 0, 0);
            float p = 0.0f;
#pragma unroll
            for (int r = 0; r < 4; ++r) p += ftanh(hacc[r]) * w2r[r];
            p += __shfl_xor(p, 16);    // fold the 4 row-groups g
            p += __shfl_xor(p, 32);
            if (g == 0 && n < BPB)
                outB[(size_t)n * NT + (t - 7 + wid)] = p + b2v;
        }

        xv = xn;
        cur = nxt;
    }
}

extern "C" void kernel_launch(void* const* d_in, const int* in_sizes, int n_in,
                              void* d_out, int out_size, void* d_ws, size_t ws_size,
                              hipStream_t stream) {
    const float* x    = (const float*)d_in[0];
    const float* W_ih = (const float*)d_in[1];
    const float* W_hh = (const float*)d_in[2];
    const float* b_ih = (const float*)d_in[3];
    const float* b_hh = (const float*)d_in[4];
    const float* W1   = (const float*)d_in[5];
    const float* b1   = (const float*)d_in[6];
    const float* W2   = (const float*)d_in[7];
    const float* b2   = (const float*)d_in[8];
    float* out = (float*)d_out;

    lstm_mfma_kernel<<<dim3(NB / BPB), dim3(512), 0, stream>>>(
        x, W_ih, W_hh, b_ih, b_hh, W1, b1, W2, b2, out);
}

// Round 7
// 272.633 us; speedup vs baseline: 1.2007x; 1.2007x over previous
//
#include <hip/hip_runtime.h>

#define NB 4096
#define NT 512
#define BPB 8    // batches per block
#define HS 40    // ushort stride per batch row (80 B, 16B-aligned)

typedef float f32x4 __attribute__((ext_vector_type(4)));
typedef short bf16x8 __attribute__((ext_vector_type(8)));

__device__ __forceinline__ float fsig(float x) {
    return __builtin_amdgcn_rcpf(1.0f + __expf(-x));
}
__device__ __forceinline__ float ftanh(float x) {
    return 2.0f * __builtin_amdgcn_rcpf(1.0f + __expf(-2.0f * x)) - 1.0f;
}
__device__ __forceinline__ unsigned cvt_pk_bf16(float a, float b) {
    unsigned r;
    asm("v_cvt_pk_bf16_f32 %0, %1, %2" : "=v"(r) : "v"(a), "v"(b));
    return r;
}
__device__ __forceinline__ unsigned short f2bf(float f) {
    unsigned u = __builtin_bit_cast(unsigned, f);
    u += 0x7fffu + ((u >> 16) & 1u);
    return (unsigned short)(u >> 16);
}
__device__ __forceinline__ float bf2f(unsigned short h) {
    return __builtin_bit_cast(float, (unsigned)h << 16);
}

// 512 blocks x 4 waves x 8 batches -> 2 blocks/CU: two INDEPENDENT barrier
// domains per CU overlap each other's chain stalls, with per-CU VALU work
// identical to the 16-batch/block layout (every thread owns a distinct
// (batch, hidden) pair). Per wave-step: 2 B-frag reads (h hi/lo, cols 8-15
// duplicate batches - redundancy lives only in the idle matrix pipe) feed 4
// independent MFMAs covering hidden 8w..8w+7; lane (g,n<8) activates
// (batch n, hidden 8w+g) from acc0, lane (g,n>=8) activates
// (batch n-8, hidden 8w+4+g) from acc1. One barrier/step. Head: every 8th
// step each wave does 2 time-slices via W1-MFMA pairs on staged th.
__global__ __launch_bounds__(256, 2) void lstm_mfma_kernel(
    const float* __restrict__ x,
    const float* __restrict__ W_ih,
    const float* __restrict__ W_hh,
    const float* __restrict__ b_ih,
    const float* __restrict__ b_hh,
    const float* __restrict__ W1,
    const float* __restrict__ b1,
    const float* __restrict__ W2,
    const float* __restrict__ b2,
    float* __restrict__ out)
{
    const int tid  = threadIdx.x;
    const int wid  = tid >> 6;        // 0..3
    const int lane = tid & 63;
    const int g    = lane >> 4;       // 0..3 : k-slice / C row-group
    const int n    = lane & 15;       // MFMA column
    const int nb   = n & 7;           // batch within block (cols 8-15 dup)
    const bool hiH = (n < 8);
    const int ja   = 8 * wid + g;     // hidden unit of acc0 rows
    const int jb   = ja + 4;          // hidden unit of acc1 rows
    const int jm   = hiH ? ja : jb;   // hidden unit this lane activates
    const int batch0 = blockIdx.x * BPB;

    __shared__ __align__(16) unsigned short sh_h[2][2][BPB][HS]; // [buf][hi/lo][nb][j]
    __shared__ __align__(16) unsigned short sh_t[2][8][BPB][HS]; // [buf][tc][nb][j]

    // ---- A fragments: tile rows m -> gate (m&3), hidden 8w+(m>>2)(+4) ----
    bf16x8 afrag0, afrag1;
    {
        const int m = lane & 15;
        const int gr0 = (m & 3) * 32 + 8 * wid + (m >> 2);
        const float* w0 = W_hh + gr0 * 32 + 8 * g;
        const float* w1p = W_hh + (gr0 + 4) * 32 + 8 * g;
#pragma unroll
        for (int i = 0; i < 8; ++i) {
            afrag0[i] = (short)f2bf(w0[i]);
            afrag1[i] = (short)f2bf(w1p[i]);
        }
    }

    // ---- per-lane gate params for hidden ja (acc0 rows) and jb (acc1) ----
    float bsA[4], wxA[4], wyA[4], bsB[4], wxB[4], wyB[4];
#pragma unroll
    for (int r = 0; r < 4; ++r) {
        const int rowA = r * 32 + ja;
        const int rowB = r * 32 + jb;
        wxA[r] = W_ih[rowA * 2 + 0];
        wyA[r] = W_ih[rowA * 2 + 1];
        bsA[r] = b_ih[rowA] + b_hh[rowA];
        wxB[r] = W_ih[rowB * 2 + 0];
        wyB[r] = W_ih[rowB * 2 + 1];
        bsB[r] = b_ih[rowB] + b_hh[rowB];
    }

    // ---- head A fragment: W1 rows m=lane&15, split bf16 hi+lo ----
    bf16x8 w1hi, w1lo;
    {
        const float* wp = W1 + (lane & 15) * 32 + 8 * g;
#pragma unroll
        for (int i = 0; i < 8; ++i) {
            const float w = wp[i];
            const unsigned short hi = f2bf(w);
            w1hi[i] = (short)hi;
            w1lo[i] = (short)f2bf(w - bf2f(hi));
        }
    }
    float b1r[4], w2r[4];
#pragma unroll
    for (int r = 0; r < 4; ++r) {
        b1r[r] = b1[4 * g + r];
        w2r[r] = W2[4 * g + r];
    }
    const float b2v = b2[0];

    // ---- zero-init h state ----
    {
        unsigned short* ph = (unsigned short*)sh_h;
        for (int i = tid; i < 2 * 2 * BPB * HS; i += 256) ph[i] = 0;
    }
    __syncthreads();

    const float2* xp = (const float2*)x + (size_t)(batch0 + nb) * NT;
    float2 xv = xp[0];
    float c = 0.0f;
    float* outB = out + (size_t)batch0 * NT;

    int cur = 0;
    for (int t = 0; t < NT; ++t) {
        // ---- B fragments first (longest latency) ----
        const bf16x8 bhi = *(const bf16x8*)&sh_h[cur][0][nb][8 * g];
        const bf16x8 blo = *(const bf16x8*)&sh_h[cur][1][nb][8 * g];

        // C init = biases + W_ih * x_t (fp32), both hidden sets
        f32x4 acc0, acc1;
#pragma unroll
        for (int r = 0; r < 4; ++r) {
            acc0[r] = fmaf(xv.x, wxA[r], fmaf(xv.y, wyA[r], bsA[r]));
            acc1[r] = fmaf(xv.x, wxB[r], fmaf(xv.y, wyB[r], bsB[r]));
        }
        f32x4 acc0L = {0.f, 0.f, 0.f, 0.f};
        f32x4 acc1L = {0.f, 0.f, 0.f, 0.f};

        // 4 independent MFMAs: {tile0,tile1} x {h_hi,h_lo}
        acc0  = __builtin_amdgcn_mfma_f32_16x16x32_bf16(afrag0, bhi, acc0,  0, 0, 0);
        acc0L = __builtin_amdgcn_mfma_f32_16x16x32_bf16(afrag0, blo, acc0L, 0, 0, 0);
        acc1  = __builtin_amdgcn_mfma_f32_16x16x32_bf16(afrag1, bhi, acc1,  0, 0, 0);
        acc1L = __builtin_amdgcn_mfma_f32_16x16x32_bf16(afrag1, blo, acc1L, 0, 0, 0);

        const float2 xn = xp[(t + 1 < NT) ? t + 1 : t];   // prefetch

        // ---- per-lane gate select + activations for (batch nb, hidden jm) ----
        float ga0 = (hiH ? acc0[0] : acc1[0]) + (hiH ? acc0L[0] : acc1L[0]);
        float ga1 = (hiH ? acc0[1] : acc1[1]) + (hiH ? acc0L[1] : acc1L[1]);
        float ga2 = (hiH ? acc0[2] : acc1[2]) + (hiH ? acc0L[2] : acc1L[2]);
        float ga3 = (hiH ? acc0[3] : acc1[3]) + (hiH ? acc0L[3] : acc1L[3]);

        const float ig = fsig(ga0);
        const float fg = fsig(ga1);
        const float gg = ftanh(ga2);
        const float og = fsig(ga3);
        c = fmaf(fg, c, ig * gg);
        const float hk  = og * ftanh(c);
        const float thk = ftanh(hk);

        const unsigned pk0 = cvt_pk_bf16(hk, thk);
        const float hlo = hk - __builtin_bit_cast(float, pk0 << 16);
        const unsigned pk1 = cvt_pk_bf16(hlo, hlo);

        const int nxt = cur ^ 1;
        const int tb  = (t >> 3) & 1;
        sh_h[nxt][0][nb][jm] = (unsigned short)pk0;            // h hi
        sh_h[nxt][1][nb][jm] = (unsigned short)pk1;            // h lo
        sh_t[tb][t & 7][nb][jm] = (unsigned short)(pk0 >> 16); // tanh(h)
        __syncthreads();   // one barrier per step

        // ---- every 8 steps: wave handles time-slices 2*wid, 2*wid+1 ----
        if ((t & 7) == 7) {
#pragma unroll
            for (int sl = 0; sl < 2; ++sl) {
                const int s = 2 * wid + sl;
                const bf16x8 bth = *(const bf16x8*)&sh_t[tb][s][nb][8 * g];
                f32x4 ha;
#pragma unroll
                for (int r = 0; r < 4; ++r) ha[r] = b1r[r];
                ha = __builtin_amdgcn_mfma_f32_16x16x32_bf16(w1hi, bth, ha, 0, 0, 0);
                ha = __builtin_amdgcn_mfma_f32_16x16x32_bf16(w1lo, bth, ha, 0, 0, 0);
                float p = 0.0f;
#pragma unroll
                for (int r = 0; r < 4; ++r) p += ftanh(ha[r]) * w2r[r];
                p += __shfl_xor(p, 16);   // fold row-groups g
                p += __shfl_xor(p, 32);
                if (g == 0 && hiH)
                    outB[(size_t)nb * NT + (t - 7 + s)] = p + b2v;
            }
        }

        xv = xn;
        cur = nxt;
    }
}

extern "C" void kernel_launch(void* const* d_in, const int* in_sizes, int n_in,
                              void* d_out, int out_size, void* d_ws, size_t ws_size,
                              hipStream_t stream) {
    const float* x    = (const float*)d_in[0];
    const float* W_ih = (const float*)d_in[1];
    const float* W_hh = (const float*)d_in[2];
    const float* b_ih = (const float*)d_in[3];
    const float* b_hh = (const float*)d_in[4];
    const float* W1   = (const float*)d_in[5];
    const float* b1   = (const float*)d_in[6];
    const float* W2   = (const float*)d_in[7];
    const float* b2   = (const float*)d_in[8];
    float* out = (float*)d_out;

    lstm_mfma_kernel<<<dim3(NB / BPB), dim3(256), 0, stream>>>(
        x, W_ih, W_hh, b_ih, b_hh, W1, b1, W2, b2, out);
}

// Round 8
// 203.327 us; speedup vs baseline: 1.6099x; 1.3409x over previous
//
#include <hip/hip_runtime.h>

#define NB 4096
#define NT 512
#define HS 40   // ushort stride per batch row (80 B: 16B-aligned, 2-way banks = free)

typedef float f32x4 __attribute__((ext_vector_type(4)));
typedef short bf16x8 __attribute__((ext_vector_type(8)));

__device__ __forceinline__ float fsig(float x) {
    return __builtin_amdgcn_rcpf(1.0f + __expf(-x));
}
__device__ __forceinline__ float ftanh(float x) {
    return 2.0f * __builtin_amdgcn_rcpf(1.0f + __expf(-2.0f * x)) - 1.0f;
}
// one inst packs two f32->bf16 (RTNE): result = [bf16(a) | bf16(b)<<16]
__device__ __forceinline__ unsigned cvt_pk_bf16(float a, float b) {
    unsigned r;
    asm("v_cvt_pk_bf16_f32 %0, %1, %2" : "=v"(r) : "v"(a), "v"(b));
    return r;
}
// RTNE f32->bf16 (prologue / weight prep only)
__device__ __forceinline__ unsigned short f2bf(float f) {
    unsigned u = __builtin_bit_cast(unsigned, f);
    u += 0x7fffu + ((u >> 16) & 1u);
    return (unsigned short)(u >> 16);
}
__device__ __forceinline__ float bf2f(unsigned short h) {
    return __builtin_bit_cast(float, (unsigned)h << 16);
}

// 256 blocks x 8 waves x 16 batches (R5 structure). Per step, wave w computes
// its 16-row gate tile with ONE mfma_f32_16x16x32_bf16 (A = permuted W_hh,
// B = h bf16). C/D layout (col=lane&15=batch n, row-group=(lane>>4)=g) puts
// all 4 gates of hidden j=4*wid+g in one lane -> activations in-register, one
// barrier/step. h carried as single bf16 (th path was already bf16 in R5 and
// absmax sat at the fast-math floor; predicted total err ~2e-3 < 3.6e-3).
// th staged bf16 in a double-buffered 8-step chunk; every 8th step wave w
// computes the head for its time-slice with one hi/lo W1 MFMA pair.
__global__ __launch_bounds__(512, 2) void lstm_mfma_kernel(
    const float* __restrict__ x,
    const float* __restrict__ W_ih,
    const float* __restrict__ W_hh,
    const float* __restrict__ b_ih,
    const float* __restrict__ b_hh,
    const float* __restrict__ W1,
    const float* __restrict__ b1,
    const float* __restrict__ W2,
    const float* __restrict__ b2,
    float* __restrict__ out)
{
    const int tid  = threadIdx.x;
    const int wid  = tid >> 6;
    const int lane = tid & 63;
    const int g    = lane >> 4;     // row-group (C rows 4g..4g+3) / B k-slice
    const int n    = lane & 15;     // batch column
    const int j    = 4 * wid + g;   // hidden unit owned by this lane
    const int batch0 = blockIdx.x * 16;

    __shared__ __align__(16) unsigned short sh_h[2][16][HS];    // h bf16 [buf][n][j]
    __shared__ __align__(16) unsigned short sh_t[2][8][16][HS]; // tanh(h) [buf][tc][n][j]

    // ---- gate A fragment: lane holds row m=lane&15, k = 8g..8g+7 of the
    //      permuted W_hh tile (row m -> gate (m&3), hidden 4*wid+(m>>2)) ----
    bf16x8 afrag;
    {
        const int m = lane & 15;
        const int grow = (m & 3) * 32 + 4 * wid + (m >> 2);
        const float* wp = W_hh + grow * 32 + 8 * g;
#pragma unroll
        for (int i = 0; i < 8; ++i) afrag[i] = (short)f2bf(wp[i]);
    }

    // ---- per-lane gate params for hidden j: rows r*32+j ----
    float wihx[4], wihy[4], bias[4];
#pragma unroll
    for (int r = 0; r < 4; ++r) {
        const int row = r * 32 + j;
        wihx[r] = W_ih[row * 2 + 0];
        wihy[r] = W_ih[row * 2 + 1];
        bias[r] = b_ih[row] + b_hh[row];
    }

    // ---- head A fragment: W1 rows m=lane&15, split bf16 hi+lo ----
    bf16x8 w1hi, w1lo;
    {
        const float* wp = W1 + (lane & 15) * 32 + 8 * g;
#pragma unroll
        for (int i = 0; i < 8; ++i) {
            const float w = wp[i];
            const unsigned short hi = f2bf(w);
            w1hi[i] = (short)hi;
            w1lo[i] = (short)f2bf(w - bf2f(hi));
        }
    }
    float b1r[4], w2r[4];   // fc1 output d = 4g+r
#pragma unroll
    for (int r = 0; r < 4; ++r) {
        b1r[r] = b1[4 * g + r];
        w2r[r] = W2[4 * g + r];
    }
    const float b2v = b2[0];

    // ---- zero-init h state ----
    {
        unsigned short* ph = (unsigned short*)sh_h;
        for (int i = tid; i < 2 * 16 * HS; i += 512) ph[i] = 0;
    }
    __syncthreads();

    const float2* xp = (const float2*)x + (size_t)(batch0 + n) * NT;
    float2 xv = xp[0];
    float c = 0.0f;
    float* outB = out + (size_t)batch0 * NT;

    int cur = 0;
    for (int t = 0; t < NT; ++t) {
        // ---- B fragment first (longest latency) ----
        const bf16x8 bh = *(const bf16x8*)&sh_h[cur][n][8 * g];

        // C init = biases + W_ih * x_t (fp32)
        f32x4 acc;
#pragma unroll
        for (int r = 0; r < 4; ++r)
            acc[r] = fmaf(xv.x, wihx[r], fmaf(xv.y, wihy[r], bias[r]));

        // gates += W_hh * h   (single MFMA)
        acc = __builtin_amdgcn_mfma_f32_16x16x32_bf16(afrag, bh, acc, 0, 0, 0);

        const float2 xn = xp[(t + 1 < NT) ? t + 1 : t];   // prefetch

        // ---- activations (lane owns batch n, hidden j; c stays in reg) ----
        const float ig = fsig(acc[0]);
        const float fg = fsig(acc[1]);
        const float gg = ftanh(acc[2]);
        const float og = fsig(acc[3]);
        c = fmaf(fg, c, ig * gg);
        const float hk  = og * ftanh(c);
        const float thk = ftanh(hk);

        // pk0 = [bf16(hk) | bf16(thk)<<16], RTNE
        const unsigned pk0 = cvt_pk_bf16(hk, thk);

        const int nxt = cur ^ 1;
        const int tb  = (t >> 3) & 1;
        sh_h[nxt][n][j] = (unsigned short)pk0;               // h bf16
        sh_t[tb][t & 7][n][j] = (unsigned short)(pk0 >> 16); // tanh(h) bf16
        __syncthreads();   // the one barrier: h(t)/th(t) visible to all waves

        // ---- every 8 steps: wave wid computes head for time t-7+wid ----
        if ((t & 7) == 7) {
            const bf16x8 bth = *(const bf16x8*)&sh_t[tb][wid][n][8 * g];
            f32x4 hacc;
#pragma unroll
            for (int r = 0; r < 4; ++r) hacc[r] = b1r[r];
            hacc = __builtin_amdgcn_mfma_f32_16x16x32_bf16(w1hi, bth, hacc, 0, 0, 0);
            hacc = __builtin_amdgcn_mfma_f32_16x16x32_bf16(w1lo, bth, hacc, 0, 0, 0);
            float p = 0.0f;
#pragma unroll
            for (int r = 0; r < 4; ++r) p += ftanh(hacc[r]) * w2r[r];
            p += __shfl_xor(p, 16);    // fold the 4 row-groups g
            p += __shfl_xor(p, 32);
            if (g == 0)
                outB[(size_t)n * NT + (t - 7 + wid)] = p + b2v;
        }

        xv = xn;
        cur = nxt;
    }
}

extern "C" void kernel_launch(void* const* d_in, const int* in_sizes, int n_in,
                              void* d_out, int out_size, void* d_ws, size_t ws_size,
                              hipStream_t stream) {
    const float* x    = (const float*)d_in[0];
    const float* W_ih = (const float*)d_in[1];
    const float* W_hh = (const float*)d_in[2];
    const float* b_ih = (const float*)d_in[3];
    const float* b_hh = (const float*)d_in[4];
    const float* W1   = (const float*)d_in[5];
    const float* b1   = (const float*)d_in[6];
    const float* W2   = (const float*)d_in[7];
    const float* b2   = (const float*)d_in[8];
    float* out = (float*)d_out;

    lstm_mfma_kernel<<<dim3(NB / 16), dim3(512), 0, stream>>>(
        x, W_ih, W_hh, b_ih, b_hh, W1, b1, W2, b2, out);
}

// Round 9
// 192.425 us; speedup vs baseline: 1.7012x; 1.0567x over previous
//
#include <hip/hip_runtime.h>

#define NB 4096
#define NT 512
#define HS 40   // ushort stride per batch row (80 B: 16B-aligned, 2-way banks = free)

typedef float f32x4 __attribute__((ext_vector_type(4)));
typedef short bf16x8 __attribute__((ext_vector_type(8)));

__device__ __forceinline__ float frcp(float x) { return __builtin_amdgcn_rcpf(x); }
__device__ __forceinline__ float ftanh(float x) {
    return 2.0f * frcp(1.0f + __expf(-2.0f * x)) - 1.0f;
}
// one inst packs two f32->bf16 (RTNE): result = [bf16(a) | bf16(b)<<16]
__device__ __forceinline__ unsigned cvt_pk_bf16(float a, float b) {
    unsigned r;
    asm("v_cvt_pk_bf16_f32 %0, %1, %2" : "=v"(r) : "v"(a), "v"(b));
    return r;
}
// RTNE f32->bf16 (prologue / weight prep only)
__device__ __forceinline__ unsigned short f2bf(float f) {
    unsigned u = __builtin_bit_cast(unsigned, f);
    u += 0x7fffu + ((u >> 16) & 1u);
    return (unsigned short)(u >> 16);
}
__device__ __forceinline__ float bf2f(unsigned short h) {
    return __builtin_bit_cast(float, (unsigned)h << 16);
}

// 256 blocks x 8 waves x 16 batches. Per step, wave w computes its 16-row
// gate tile with ONE mfma_f32_16x16x32_bf16 (A = permuted W_hh, B = h bf16);
// C/D layout (col=lane&15=batch n, row-group=lane>>4=g) gives each lane all
// 4 gates of hidden j=4*wid+g -> activations in-register, one barrier/step.
// Critical chain per step: bar -> ds_read(h) -> MFMA -> fused act chain
// (5 exp + 3 rcp; i*g and o*tanh(c) fused through one rcp each) -> b16 write
// -> bar. tanh(h) + sh_t write + head all run POST-barrier, filling the next
// step's ds_read/MFMA latency shadow. Head consumes the previous 8-step chunk
// (times t-15..t-8) with a hi/lo W1 MFMA pair; epilogue head after the loop.
__global__ __launch_bounds__(512, 2) void lstm_mfma_kernel(
    const float* __restrict__ x,
    const float* __restrict__ W_ih,
    const float* __restrict__ W_hh,
    const float* __restrict__ b_ih,
    const float* __restrict__ b_hh,
    const float* __restrict__ W1,
    const float* __restrict__ b1,
    const float* __restrict__ W2,
    const float* __restrict__ b2,
    float* __restrict__ out)
{
    const int tid  = threadIdx.x;
    const int wid  = tid >> 6;
    const int lane = tid & 63;
    const int g    = lane >> 4;     // row-group (C rows 4g..4g+3) / B k-slice
    const int n    = lane & 15;     // batch column
    const int j    = 4 * wid + g;   // hidden unit owned by this lane
    const int batch0 = blockIdx.x * 16;

    __shared__ __align__(16) unsigned short sh_h[2][16][HS];    // h bf16 [buf][n][j]
    __shared__ __align__(16) unsigned short sh_t[2][8][16][HS]; // tanh(h) [buf][tc][n][j]

    // ---- gate A fragment: lane holds row m=lane&15, k = 8g..8g+7 of the
    //      permuted W_hh tile (row m -> gate (m&3), hidden 4*wid+(m>>2)) ----
    bf16x8 afrag;
    {
        const int m = lane & 15;
        const int grow = (m & 3) * 32 + 4 * wid + (m >> 2);
        const float* wp = W_hh + grow * 32 + 8 * g;
#pragma unroll
        for (int i = 0; i < 8; ++i) afrag[i] = (short)f2bf(wp[i]);
    }

    // ---- per-lane gate params for hidden j: rows r*32+j ----
    float wihx[4], wihy[4], bias[4];
#pragma unroll
    for (int r = 0; r < 4; ++r) {
        const int row = r * 32 + j;
        wihx[r] = W_ih[row * 2 + 0];
        wihy[r] = W_ih[row * 2 + 1];
        bias[r] = b_ih[row] + b_hh[row];
    }

    // ---- head A fragment: W1 rows m=lane&15, split bf16 hi+lo ----
    bf16x8 w1hi, w1lo;
    {
        const float* wp = W1 + (lane & 15) * 32 + 8 * g;
#pragma unroll
        for (int i = 0; i < 8; ++i) {
            const float w = wp[i];
            const unsigned short hi = f2bf(w);
            w1hi[i] = (short)hi;
            w1lo[i] = (short)f2bf(w - bf2f(hi));
        }
    }
    float b1r[4], w2r[4];   // fc1 output d = 4g+r
#pragma unroll
    for (int r = 0; r < 4; ++r) {
        b1r[r] = b1[4 * g + r];
        w2r[r] = W2[4 * g + r];
    }
    const float b2v = b2[0];

    // ---- zero-init h state ----
    {
        unsigned short* ph = (unsigned short*)sh_h;
        for (int i = tid; i < 2 * 16 * HS; i += 512) ph[i] = 0;
    }
    __syncthreads();

    const float2* xp = (const float2*)x + (size_t)(batch0 + n) * NT;
    float2 xv = xp[0];
    float c = 0.0f;
    float* outB = out + (size_t)batch0 * NT;

    // head for time base+wid from chunk buffer `buf`
#define HEAD(buf, base)                                                        \
    {                                                                          \
        const bf16x8 bth = *(const bf16x8*)&sh_t[buf][wid][n][8 * g];          \
        f32x4 hacc;                                                            \
        _Pragma("unroll")                                                      \
        for (int r = 0; r < 4; ++r) hacc[r] = b1r[r];                          \
        hacc = __builtin_amdgcn_mfma_f32_16x16x32_bf16(w1hi, bth, hacc, 0,0,0);\
        hacc = __builtin_amdgcn_mfma_f32_16x16x32_bf16(w1lo, bth, hacc, 0,0,0);\
        float p = 0.0f;                                                        \
        _Pragma("unroll")                                                      \
        for (int r = 0; r < 4; ++r) p += ftanh(hacc[r]) * w2r[r];              \
        p += __shfl_xor(p, 16);                                                \
        p += __shfl_xor(p, 32);                                                \
        if (g == 0) outB[(size_t)n * NT + ((base) + wid)] = p + b2v;           \
    }

    int cur = 0;
    for (int t = 0; t < NT; ++t) {
        // ---- critical chain: read h(t-1), MFMA, activations, write h(t) ----
        const bf16x8 bh = *(const bf16x8*)&sh_h[cur][n][8 * g];

        f32x4 acc;   // C init = biases + W_ih * x_t (fp32)
#pragma unroll
        for (int r = 0; r < 4; ++r)
            acc[r] = fmaf(xv.x, wihx[r], fmaf(xv.y, wihy[r], bias[r]));

        acc = __builtin_amdgcn_mfma_f32_16x16x32_bf16(afrag, bh, acc, 0, 0, 0);

        const float2 xn = xp[(t + 1 < NT) ? t + 1 : t];   // prefetch

        // fused activations: 5 exp + 3 rcp (i*g and o*tanh(c) share one rcp)
        const float p0 = __expf(-acc[0]);          // e^-a_i
        const float p1 = __expf(-acc[1]);          // e^-a_f
        const float q2 = __expf(-2.0f * acc[2]);   // e^-2a_g
        const float p3 = __expf(-acc[3]);          // e^-a_o
        const float igg = (1.0f - q2) * frcp((1.0f + p0) * (1.0f + q2)); // i*g
        const float fg  = frcp(1.0f + p1);                               // f
        c = fmaf(fg, c, igg);
        const float qc = __expf(-2.0f * c);
        const float hk = (1.0f - qc) * frcp((1.0f + p3) * (1.0f + qc));  // o*tanh(c)

        const int nxt = cur ^ 1;
        sh_h[nxt][n][j] = (unsigned short)cvt_pk_bf16(hk, hk);   // h bf16
        __syncthreads();   // h(t) visible; thk/head run in next read's shadow

        // ---- post-barrier (off the recurrence chain) ----
        const int tb = (t >> 3) & 1;
        const float thk = ftanh(hk);
        sh_t[tb][t & 7][n][j] = (unsigned short)cvt_pk_bf16(thk, thk);

        if ((t & 7) == 7 && t != 7)
            HEAD(tb ^ 1, t - 15)    // times t-15 .. t-8 (previous chunk)

        xv = xn;
        cur = nxt;
    }

    // epilogue: last chunk (times 504..511, buffer 1)
    __syncthreads();
    HEAD(1, NT - 8)
#undef HEAD
}

extern "C" void kernel_launch(void* const* d_in, const int* in_sizes, int n_in,
                              void* d_out, int out_size, void* d_ws, size_t ws_size,
                              hipStream_t stream) {
    const float* x    = (const float*)d_in[0];
    const float* W_ih = (const float*)d_in[1];
    const float* W_hh = (const float*)d_in[2];
    const float* b_ih = (const float*)d_in[3];
    const float* b_hh = (const float*)d_in[4];
    const float* W1   = (const float*)d_in[5];
    const float* b1   = (const float*)d_in[6];
    const float* W2   = (const float*)d_in[7];
    const float* b2   = (const float*)d_in[8];
    float* out = (float*)d_out;

    lstm_mfma_kernel<<<dim3(NB / 16), dim3(512), 0, stream>>>(
        x, W_ih, W_hh, b_ih, b_hh, W1, b1, W2, b2, out);
}

// Round 11
// 189.586 us; speedup vs baseline: 1.7266x; 1.0150x over previous
//
#include <hip/hip_runtime.h>

#define NB 4096
#define NT 512
#define HS 40   // ushort stride per batch row (80 B: 16B-aligned, 2-way banks = free)

typedef float f32x4 __attribute__((ext_vector_type(4)));
typedef short bf16x8 __attribute__((ext_vector_type(8)));

#define L2E  1.4426950408889634f   // log2(e)
#define L2E2 2.8853900817779268f   // 2*log2(e)

// ocml native exp2 -> single v_exp_f32, compiler-visible (no inline asm)
extern "C" __device__ float __ocml_native_exp2_f32(float);
__device__ __forceinline__ float ex2(float x) { return __ocml_native_exp2_f32(x); }

__device__ __forceinline__ float frcp(float x) { return __builtin_amdgcn_rcpf(x); }
__device__ __forceinline__ float ftanh(float x) {   // off-chain users only
    return 2.0f * frcp(1.0f + __expf(-2.0f * x)) - 1.0f;
}
// one inst packs two f32->bf16 (RTNE): result = [bf16(a) | bf16(b)<<16]
__device__ __forceinline__ unsigned cvt_pk_bf16(float a, float b) {
    unsigned r;
    asm("v_cvt_pk_bf16_f32 %0, %1, %2" : "=v"(r) : "v"(a), "v"(b));
    return r;
}
// RTNE f32->bf16 (prologue / weight prep only)
__device__ __forceinline__ unsigned short f2bf(float f) {
    unsigned u = __builtin_bit_cast(unsigned, f);
    u += 0x7fffu + ((u >> 16) & 1u);
    return (unsigned short)(u >> 16);
}
__device__ __forceinline__ float bf2f(unsigned short h) {
    return __builtin_bit_cast(float, (unsigned)h << 16);
}

// 256 blocks x 8 waves x 16 batches (R9 structure, memory path unchanged).
// Per step, wave w computes its 16-row gate tile with ONE
// mfma_f32_16x16x32_bf16 (A = permuted W_hh, B = h bf16); C/D layout
// (col=lane&15=batch n, row-group=lane>>4=g) gives each lane all 4 gates of
// hidden j=4*wid+g -> activations in-register, one barrier/step.
// Gate rows are prescaled by -log2e (-2log2e for the g-gate row) at weight
// load, so every activation exp is a BARE exp2: p_r = 2^(acc_r) = e^(-a_r);
// c is carried negated-scaled as ctilm = -2log2e*c. Chain per step:
// bar -> ds_read_b128 -> MFMA -> 5 exp2 + 3 rcp fused acts -> b16 write ->
// bar. tanh(h), sh_t write and the chunked head (hi/lo W1 MFMA pair per 8
// steps) run post-barrier in the next step's read/MFMA shadow.
__global__ __launch_bounds__(512, 2) void lstm_mfma_kernel(
    const float* __restrict__ x,
    const float* __restrict__ W_ih,
    const float* __restrict__ W_hh,
    const float* __restrict__ b_ih,
    const float* __restrict__ b_hh,
    const float* __restrict__ W1,
    const float* __restrict__ b1,
    const float* __restrict__ W2,
    const float* __restrict__ b2,
    float* __restrict__ out)
{
    const int tid  = threadIdx.x;
    const int wid  = tid >> 6;
    const int lane = tid & 63;
    const int g    = lane >> 4;     // row-group (C rows 4g..4g+3) / B k-slice
    const int n    = lane & 15;     // batch column
    const int j    = 4 * wid + g;   // hidden unit owned by this lane
    const int batch0 = blockIdx.x * 16;

    __shared__ __align__(16) unsigned short sh_h[2][16][HS];    // h bf16 [buf][n][j]
    __shared__ __align__(16) unsigned short sh_t[2][8][16][HS]; // tanh(h) [buf][tc][n][j]

    // ---- gate A fragment: lane holds row m=lane&15, k = 8g..8g+7 of the
    //      permuted W_hh tile (row m -> gate (m&3), hidden 4*wid+(m>>2)),
    //      prescaled by -log2e (g-gate row: -2log2e) ----
    bf16x8 afrag;
    {
        const int m = lane & 15;
        const float nsc = ((m & 3) == 2) ? -L2E2 : -L2E;
        const int grow = (m & 3) * 32 + 4 * wid + (m >> 2);
        const float* wp = W_hh + grow * 32 + 8 * g;
#pragma unroll
        for (int i = 0; i < 8; ++i) afrag[i] = (short)f2bf(wp[i] * nsc);
    }

    // ---- per-lane gate params for hidden j: rows r*32+j, prescaled ----
    float wihx[4], wihy[4], bias[4];
#pragma unroll
    for (int r = 0; r < 4; ++r) {
        const float nsc = (r == 2) ? -L2E2 : -L2E;
        const int row = r * 32 + j;
        wihx[r] = W_ih[row * 2 + 0] * nsc;
        wihy[r] = W_ih[row * 2 + 1] * nsc;
        bias[r] = (b_ih[row] + b_hh[row]) * nsc;
    }

    // ---- head A fragment: W1 rows m=lane&15, split bf16 hi+lo (unscaled) ----
    bf16x8 w1hi, w1lo;
    {
        const float* wp = W1 + (lane & 15) * 32 + 8 * g;
#pragma unroll
        for (int i = 0; i < 8; ++i) {
            const float w = wp[i];
            const unsigned short hi = f2bf(w);
            w1hi[i] = (short)hi;
            w1lo[i] = (short)f2bf(w - bf2f(hi));
        }
    }
    float b1r[4], w2r[4];   // fc1 output d = 4g+r
#pragma unroll
    for (int r = 0; r < 4; ++r) {
        b1r[r] = b1[4 * g + r];
        w2r[r] = W2[4 * g + r];
    }
    const float b2v = b2[0];

    // ---- zero-init h state ----
    {
        unsigned short* ph = (unsigned short*)sh_h;
        for (int i = tid; i < 2 * 16 * HS; i += 512) ph[i] = 0;
    }
    __syncthreads();

    const float2* xp = (const float2*)x + (size_t)(batch0 + n) * NT;
    float2 xv = xp[0];
    float ctilm = 0.0f;   // -2*log2e * c
    float* outB = out + (size_t)batch0 * NT;

    // head for time base+wid from chunk buffer `buf`
#define HEAD(buf, base)                                                        \
    {                                                                          \
        const bf16x8 bth = *(const bf16x8*)&sh_t[buf][wid][n][8 * g];          \
        f32x4 hacc;                                                            \
        _Pragma("unroll")                                                      \
        for (int r = 0; r < 4; ++r) hacc[r] = b1r[r];                          \
        hacc = __builtin_amdgcn_mfma_f32_16x16x32_bf16(w1hi, bth, hacc, 0,0,0);\
        hacc = __builtin_amdgcn_mfma_f32_16x16x32_bf16(w1lo, bth, hacc, 0,0,0);\
        float p = 0.0f;                                                        \
        _Pragma("unroll")                                                      \
        for (int r = 0; r < 4; ++r) p += ftanh(hacc[r]) * w2r[r];              \
        p += __shfl_xor(p, 16);                                                \
        p += __shfl_xor(p, 32);                                                \
        if (g == 0) outB[(size_t)n * NT + ((base) + wid)] = p + b2v;           \
    }

    int cur = 0;
    for (int t = 0; t < NT; ++t) {
        // ---- critical chain: read h(t-1), MFMA, activations, write h(t) ----
        const bf16x8 bh = *(const bf16x8*)&sh_h[cur][n][8 * g];

        f32x4 acc;   // C init = neg-scaled biases + neg-scaled W_ih * x_t
#pragma unroll
        for (int r = 0; r < 4; ++r)
            acc[r] = fmaf(xv.x, wihx[r], fmaf(xv.y, wihy[r], bias[r]));

        acc = __builtin_amdgcn_mfma_f32_16x16x32_bf16(afrag, bh, acc, 0, 0, 0);

        const float2 xn = xp[(t + 1 < NT) ? t + 1 : t];   // prefetch

        // fused activations: acc[r] = -log2e*a_r (g-row: -2log2e*a_g)
        // -> every exp is a bare exp2; 5 exp2 + 3 rcp total
        const float p0 = ex2(acc[0]);              // e^-a_i
        const float p1 = ex2(acc[1]);              // e^-a_f
        const float q2 = ex2(acc[2]);              // e^-2a_g
        const float p3 = ex2(acc[3]);              // e^-a_o
        const float igg = (1.0f - q2) * frcp((1.0f + p0) * (1.0f + q2)); // i*g
        const float fg  = frcp(1.0f + p1);                               // f
        ctilm = fmaf(fg, ctilm, -L2E2 * igg);      // ctilm = -2log2e*c
        const float qc = ex2(ctilm);               // e^-2c
        const float hk = (1.0f - qc) * frcp((1.0f + p3) * (1.0f + qc));  // o*tanh(c)

        const int nxt = cur ^ 1;
        sh_h[nxt][n][j] = (unsigned short)cvt_pk_bf16(hk, hk);   // h bf16
        __syncthreads();   // h(t) visible; thk/head run in next read's shadow

        // ---- post-barrier (off the recurrence chain) ----
        const int tb = (t >> 3) & 1;
        const float thk = ftanh(hk);
        sh_t[tb][t & 7][n][j] = (unsigned short)cvt_pk_bf16(thk, thk);

        if ((t & 7) == 7 && t != 7)
            HEAD(tb ^ 1, t - 15)    // times t-15 .. t-8 (previous chunk)

        xv = xn;
        cur = nxt;
    }

    // epilogue: last chunk (times 504..511, buffer 1)
    __syncthreads();
    HEAD(1, NT - 8)
#undef HEAD
}

extern "C" void kernel_launch(void* const* d_in, const int* in_sizes, int n_in,
                              void* d_out, int out_size, void* d_ws, size_t ws_size,
                              hipStream_t stream) {
    const float* x    = (const float*)d_in[0];
    const float* W_ih = (const float*)d_in[1];
    const float* W_hh = (const float*)d_in[2];
    const float* b_ih = (const float*)d_in[3];
    const float* b_hh = (const float*)d_in[4];
    const float* W1   = (const float*)d_in[5];
    const float* b1   = (const float*)d_in[6];
    const float* W2   = (const float*)d_in[7];
    const float* b2   = (const float*)d_in[8];
    float* out = (float*)d_out;

    lstm_mfma_kernel<<<dim3(NB / 16), dim3(512), 0, stream>>>(
        x, W_ih, W_hh, b_ih, b_hh, W1, b1, W2, b2, out);
}